// Round 1
// baseline (1147.538 us; speedup 1.0000x reference)
//
#include <hip/hip_runtime.h>
#include <hip/hip_bf16.h>

#define HIDDEN 128
#define NRAD 6
#define EPG 4          // edges per wave-iteration
#define WPB 8          // waves per block (512 threads)

__device__ __forceinline__ float silu_f(float z) {
    return z / (1.0f + __expf(-z));
}

// ---------------------------------------------------------------------------
// Kernel A: per-type projected tables + W3 transpose.
//   T1[t][h] = lin_b[h] + sum_k lin_w[h][k]       * emb_w[t][k]
//   T2[t][h] =            sum_k lin_w[h][128+k]   * emb_w[t][k]
//   W3T[c][h] = lin_w[h][256+c]
// blocks 0..n_types-1: type tables (128 threads, thread = h)
// blocks n_types..n_types+31: transpose slices
// ---------------------------------------------------------------------------
__global__ void build_tables(const float* __restrict__ emb_w,
                             const float* __restrict__ lin_w,
                             const float* __restrict__ lin_b,
                             float* __restrict__ T1,
                             float* __restrict__ T2,
                             float* __restrict__ W3T,
                             int n_types)
{
    __shared__ float hv[HIDDEN];
    int b = blockIdx.x;
    int h = threadIdx.x;          // 0..127
    if (b < n_types) {
        hv[h] = emb_w[b * HIDDEN + h];
        __syncthreads();
        float a1 = lin_b[h];
        float a2 = 0.0f;
        const float* wrow = lin_w + (size_t)h * (3 * HIDDEN);
        #pragma unroll 8
        for (int k = 0; k < HIDDEN; ++k) {
            float e = hv[k];
            a1 = fmaf(wrow[k], e, a1);
            a2 = fmaf(wrow[HIDDEN + k], e, a2);
        }
        T1[b * HIDDEN + h] = a1;
        T2[b * HIDDEN + h] = a2;
    } else {
        int tb = b - n_types;                 // 0..31, 512 elements each
        #pragma unroll
        for (int q = 0; q < 4; ++q) {
            int idx = tb * 512 + q * 128 + h; // 0..16383
            int c = idx >> 7;
            int hh = idx & 127;
            W3T[idx] = lin_w[(size_t)hh * (3 * HIDDEN) + 2 * HIDDEN + c];
        }
    }
}

// ---------------------------------------------------------------------------
// Main edge kernel.
// out[e][h] = silu( T1[x[i[e]]][h] + T2[x[j[e]]][h]
//                   + sum_c W3T[c][h] * silu(rbf[e] . rbf_w[c] + rbf_b[c]) )
// One wave processes EPG edges per iteration; lane owns h = 2*lane, 2*lane+1.
// ---------------------------------------------------------------------------
__global__ __launch_bounds__(512, 4)
void edge_kernel(const int*   __restrict__ x,
                 const float* __restrict__ rbf,
                 const int*   __restrict__ ei,
                 const int*   __restrict__ ej,
                 const float* __restrict__ rbf_w,   // [128][6]
                 const float* __restrict__ rbf_b,   // [128]
                 const float* __restrict__ T1,
                 const float* __restrict__ T2,
                 const float* __restrict__ W3T,     // [c][h]
                 float*       __restrict__ out,
                 int E)
{
    __shared__ float W3s[HIDDEN * HIDDEN];          // 64 KB, [c][h]
    __shared__ float sbuf[WPB][EPG][HIDDEN];        // 16 KB

    int tid = threadIdx.x;

    // stage W3T -> LDS, coalesced float4
    for (int idx = tid * 4; idx < HIDDEN * HIDDEN; idx += 512 * 4)
        *(float4*)&W3s[idx] = *(const float4*)&W3T[idx];
    __syncthreads();

    int lane = tid & 63;
    int w = __builtin_amdgcn_readfirstlane(tid >> 6);
    float* sb = &sbuf[w][0][0];

    // hoist rbf first-layer weights into registers (c = lane and lane+64)
    float wr0[NRAD], wr1[NRAD];
    #pragma unroll
    for (int r = 0; r < NRAD; ++r) {
        wr0[r] = rbf_w[lane * NRAD + r];
        wr1[r] = rbf_w[(lane + 64) * NRAD + r];
    }
    float br0 = rbf_b[lane];
    float br1 = rbf_b[lane + 64];

    int h2 = 2 * lane;

    long gw = (long)blockIdx.x * WPB + w;
    long nw = (long)gridDim.x * WPB;
    long ngroups = ((long)E + EPG - 1) / EPG;

    for (long g = gw; g < ngroups; g += nw) {
        int e0 = (int)(g * EPG);
        int eidx[EPG];
        #pragma unroll
        for (int k = 0; k < EPG; ++k) {
            int e = e0 + k;
            eidx[k] = (e < E) ? e : (E - 1);
        }

        // init accumulators from type-table gathers (issue loads early)
        float2 acc[EPG];
        #pragma unroll
        for (int k = 0; k < EPG; ++k) {
            int xi = x[ei[eidx[k]]];
            int xj = x[ej[eidx[k]]];
            float2 a = *(const float2*)&T1[xi * HIDDEN + h2];
            float2 b = *(const float2*)&T2[xj * HIDDEN + h2];
            acc[k].x = a.x + b.x;
            acc[k].y = a.y + b.y;
        }

        // rbf hidden layer -> per-wave LDS buffer
        #pragma unroll
        for (int k = 0; k < EPG; ++k) {
            const float* rv = rbf + (long)eidx[k] * NRAD;
            float z0 = br0, z1 = br1;
            #pragma unroll
            for (int r = 0; r < NRAD; ++r) {
                float rr = rv[r];
                z0 = fmaf(wr0[r], rr, z0);
                z1 = fmaf(wr1[r], rr, z1);
            }
            sb[k * HIDDEN + lane]      = silu_f(z0);
            sb[k * HIDDEN + 64 + lane] = silu_f(z1);
        }
        // per-wave LDS RAW fence: drain ds_writes, block compiler reordering
        asm volatile("s_waitcnt lgkmcnt(0)" ::: "memory");

        // MAC: acc[k][h] += sum_c W3s[c][h] * s[k][c]
        #pragma unroll 1
        for (int c = 0; c < HIDDEN; c += 4) {
            float4 s0 = *(const float4*)&sb[0 * HIDDEN + c];
            float4 s1 = *(const float4*)&sb[1 * HIDDEN + c];
            float4 s2 = *(const float4*)&sb[2 * HIDDEN + c];
            float4 s3 = *(const float4*)&sb[3 * HIDDEN + c];
            float sA[4] = {s0.x, s0.y, s0.z, s0.w};
            float sB[4] = {s1.x, s1.y, s1.z, s1.w};
            float sC[4] = {s2.x, s2.y, s2.z, s2.w};
            float sD[4] = {s3.x, s3.y, s3.z, s3.w};
            #pragma unroll
            for (int cc = 0; cc < 4; ++cc) {
                float2 wv = *(const float2*)&W3s[(c + cc) * HIDDEN + h2];
                acc[0].x = fmaf(wv.x, sA[cc], acc[0].x);
                acc[0].y = fmaf(wv.y, sA[cc], acc[0].y);
                acc[1].x = fmaf(wv.x, sB[cc], acc[1].x);
                acc[1].y = fmaf(wv.y, sB[cc], acc[1].y);
                acc[2].x = fmaf(wv.x, sC[cc], acc[2].x);
                acc[2].y = fmaf(wv.y, sC[cc], acc[2].y);
                acc[3].x = fmaf(wv.x, sD[cc], acc[3].x);
                acc[3].y = fmaf(wv.y, sD[cc], acc[3].y);
            }
        }

        // epilogue: silu + coalesced float2 store
        #pragma unroll
        for (int k = 0; k < EPG; ++k) {
            int e = e0 + k;
            if (e < E) {
                float2 o;
                o.x = silu_f(acc[k].x);
                o.y = silu_f(acc[k].y);
                *(float2*)&out[(long)e * HIDDEN + h2] = o;
            }
        }
    }
}

// ---------------------------------------------------------------------------
extern "C" void kernel_launch(void* const* d_in, const int* in_sizes, int n_in,
                              void* d_out, int out_size, void* d_ws, size_t ws_size,
                              hipStream_t stream)
{
    const int*   x         = (const int*)  d_in[0];
    const float* rbf       = (const float*)d_in[1];
    const int*   ei        = (const int*)  d_in[2];
    const int*   ej        = (const int*)  d_in[3];
    const float* emb_w     = (const float*)d_in[4];
    const float* lin_rbf_w = (const float*)d_in[5];
    const float* lin_rbf_b = (const float*)d_in[6];
    const float* lin_w     = (const float*)d_in[7];
    const float* lin_b     = (const float*)d_in[8];

    int E  = in_sizes[2];                 // edge count
    int NT = in_sizes[4] / HIDDEN;        // number of node types (95)

    // workspace layout: T1 | T2 | W3T   (needs (2*NT*128 + 16384)*4 B ~ 159 KB)
    float* T1  = (float*)d_ws;
    float* T2  = T1 + (size_t)NT * HIDDEN;
    float* W3T = T2 + (size_t)NT * HIDDEN;

    hipLaunchKernelGGL(build_tables, dim3(NT + 32), dim3(HIDDEN), 0, stream,
                       emb_w, lin_w, lin_b, T1, T2, W3T, NT);

    // 2 blocks/CU * 256 CU; grid-stride inside
    hipLaunchKernelGGL(edge_kernel, dim3(512), dim3(512), 0, stream,
                       x, rbf, ei, ej, lin_rbf_w, lin_rbf_b,
                       T1, T2, W3T, (float*)d_out, E);
}